// Round 1
// 2235.068 us; speedup vs baseline: 1.5181x; 1.5181x over previous
//
#include <hip/hip_runtime.h>
#include <hip/hip_bf16.h>
#include <math.h>

constexpr int Vv   = 50257;
constexpr int Vpad = 50304;          // 393 * 128
constexpr int Dd   = 512;
constexpr int Hh   = 8;
constexpr int Ll   = 6;
constexpr int Ss   = 1024;
constexpr int Bb   = 2;
constexpr int NT   = Bb * Ss;        // 2048
constexpr int Dff  = 2048;
constexpr float INV_SCALE = 0.04419417382415922f; // 1/sqrt(512)

typedef __hip_bfloat16 bf16;
typedef __attribute__((ext_vector_type(8))) short bf16x8;
typedef __attribute__((ext_vector_type(4))) float f32x4;

__device__ inline float wave_sum(float x) {
#pragma unroll
  for (int off = 32; off > 0; off >>= 1) x += __shfl_xor(x, off, 64);
  return x;
}

// async global->LDS, 16B per lane, dst = wave-uniform base + lane*16
__device__ inline void gl_lds16(const bf16* g, bf16* l) {
  __builtin_amdgcn_global_load_lds((__attribute__((address_space(1))) void*)g,
                                   (__attribute__((address_space(3))) void*)l,
                                   16, 0, 0);
}

// ---------------- prep: transpose fp32 [K,N] -> bf16 [Npad,K] (times scale) ----
__global__ __launch_bounds__(256) void transpose_bf16(
    const float* __restrict__ src, bf16* __restrict__ dst,
    int K, int N, int Npad, long srcStride, long dstStride, float scale) {
  __shared__ float tile[32][33];
  const float* s = src + (size_t)blockIdx.z * srcStride;
  bf16* d = dst + (size_t)blockIdx.z * dstStride;
  int n0 = blockIdx.x * 32, k0 = blockIdx.y * 32;
  int tr = threadIdx.x >> 5, tc = threadIdx.x & 31;
#pragma unroll
  for (int i = 0; i < 4; i++) {
    int k = k0 + tr + i * 8, n = n0 + tc;
    tile[tr + i * 8][tc] = (k < K && n < N) ? s[(size_t)k * N + n] * scale : 0.f;
  }
  __syncthreads();
#pragma unroll
  for (int i = 0; i < 4; i++) {
    int n = n0 + tr + i * 8, k = k0 + tc;
    if (n < Npad && k < K) d[(size_t)n * K + k] = __float2bfloat16(tile[tc][tr + i * 8]);
  }
}

__global__ void concat_bias(const float* __restrict__ bq, const float* __restrict__ bk,
                            const float* __restrict__ bv, float* __restrict__ dst) {
  int i = blockIdx.x * 256 + threadIdx.x;
  if (i >= Ll * 1536) return;
  int l = i / 1536, j = i - l * 1536;
  float v = (j < 512) ? bq[l * 512 + j] * INV_SCALE
          : (j < 1024) ? bk[l * 512 + j - 512]
                       : bv[l * 512 + j - 1024];
  dst[i] = v;
}

// ---------------- embed ----------------
__global__ void embed_kernel(const int* __restrict__ idx, const int* __restrict__ masks,
                             const float* __restrict__ tok, const float* __restrict__ pos,
                             float* __restrict__ x) {
  int i = blockIdx.x * blockDim.x + threadIdx.x;
  if (i >= NT * Dd) return;
  int d = i & (Dd - 1);
  int row = i >> 9;
  int s = row & (Ss - 1);
  int b = row >> 10;
  int t = idx[b * (Ss + 1) + s];
  float m = (float)masks[row];
  x[i] = (tok[(size_t)t * Dd + d] + pos[s * Dd + d]) * m;
}

// ---------------- LayerNorm: fp32 in, bf16 out; 4 rows/block ----------------
__global__ __launch_bounds__(256) void ln_kernel(const float* __restrict__ x,
                                                 const float* __restrict__ g,
                                                 const float* __restrict__ b,
                                                 bf16* __restrict__ out) {
  int row = blockIdx.x * 4 + (threadIdx.x >> 6);
  int lane = threadIdx.x & 63;
  const float* xr = x + (size_t)row * Dd;
  float vals[8];
  float s = 0.f;
#pragma unroll
  for (int i = 0; i < 8; i++) { vals[i] = xr[lane + i * 64]; s += vals[i]; }
  s = wave_sum(s);
  float mean = s * (1.f / Dd);
  float vs = 0.f;
#pragma unroll
  for (int i = 0; i < 8; i++) { float dd = vals[i] - mean; vs += dd * dd; }
  vs = wave_sum(vs);
  float rstd = rsqrtf(vs * (1.f / Dd) + 1e-5f);
  bf16* orow = out + (size_t)row * Dd;
#pragma unroll
  for (int i = 0; i < 8; i++) {
    int d = lane + i * 64;
    orow[d] = __float2bfloat16((vals[i] - mean) * rstd * g[d] + b[d]);
  }
}

// ---------------- MFMA GEMM (m97 structure) ----------------
// C[M,N] = epilogue( A[M,K]bf16 @ Bt[N,K]bf16^T + bias ) (+resid) -> fp32 or bf16
// 128x128 tile, BK=32, 256 threads (4 waves, each 64x64 via 4x4 of 16x16x32 MFMA)
__global__ __launch_bounds__(256) void mfma_gemm(
    const bf16* __restrict__ A, const bf16* __restrict__ Bt,
    const float* __restrict__ bias, const float* __restrict__ resid,
    float* __restrict__ Cf, bf16* __restrict__ Cb,
    int M, int N, int K, int act) {
  __shared__ bf16 As[128 * 32];
  __shared__ bf16 Bs[128 * 32];
  const int t = threadIdx.x;
  const int w = t >> 6, lane = t & 63;
  const int m0 = blockIdx.y * 128, n0 = blockIdx.x * 128;
  const int rr = lane >> 2;            // 0..15 rows per load inst
  const int cc = (lane & 3) * 8;       // elem col within BK
  const bf16* ap0 = A  + (size_t)(m0 + w * 32 + rr) * K + cc;
  const bf16* ap1 = ap0 + (size_t)16 * K;
  const bf16* bp0 = Bt + (size_t)(n0 + w * 32 + rr) * K + cc;
  const bf16* bp1 = bp0 + (size_t)16 * K;
  bf16* as0 = As + w * 32 * 32;
  bf16* as1 = as0 + 16 * 32;
  bf16* bs0 = Bs + w * 32 * 32;
  bf16* bs1 = bs0 + 16 * 32;
  const int wr = (w >> 1) * 64, wc = (w & 1) * 64;
  const int lm = lane & 15, lk = (lane >> 4) * 8;
  f32x4 acc[4][4];
#pragma unroll
  for (int i = 0; i < 4; i++)
#pragma unroll
    for (int j = 0; j < 4; j++) acc[i][j] = (f32x4){0.f, 0.f, 0.f, 0.f};

  for (int k0 = 0; k0 < K; k0 += 32) {
    __syncthreads();
    gl_lds16(ap0 + k0, as0);
    gl_lds16(ap1 + k0, as1);
    gl_lds16(bp0 + k0, bs0);
    gl_lds16(bp1 + k0, bs1);
    __syncthreads();
    bf16x8 af[4], bg[4];
#pragma unroll
    for (int i = 0; i < 4; i++)
      af[i] = *(const bf16x8*)(As + (wr + i * 16 + lm) * 32 + lk);
#pragma unroll
    for (int j = 0; j < 4; j++)
      bg[j] = *(const bf16x8*)(Bs + (wc + j * 16 + lm) * 32 + lk);
#pragma unroll
    for (int i = 0; i < 4; i++)
#pragma unroll
      for (int j = 0; j < 4; j++)
        acc[i][j] = __builtin_amdgcn_mfma_f32_16x16x32_bf16(af[i], bg[j], acc[i][j], 0, 0, 0);
  }

  const int r4 = (lane >> 4) * 4;
#pragma unroll
  for (int i = 0; i < 4; i++) {
#pragma unroll
    for (int j = 0; j < 4; j++) {
      int col = n0 + wc + j * 16 + lm;
      if (col >= N) continue;
      float bi = bias ? bias[col] : 0.f;
#pragma unroll
      for (int r = 0; r < 4; r++) {
        int row = m0 + wr + i * 16 + r4 + r;
        float v = acc[i][j][r] + bi;
        if (act) v = 0.5f * v * (1.f + erff(v * 0.70710678118654752f));
        if (resid) v += resid[(size_t)row * N + col];
        if (Cf) Cf[(size_t)row * N + col] = v;
        else    Cb[(size_t)row * N + col] = __float2bfloat16(v);
      }
    }
  }
}

// ---------------- V transpose: qkv bf16 [NT,1536] -> vT bf16 [B*H, 64, Ss] ----
__global__ __launch_bounds__(256) void v_transpose(const bf16* __restrict__ qkv,
                                                   bf16* __restrict__ vT) {
  __shared__ alignas(16) bf16 tile[64][72];
  const int bx = blockIdx.x, bh = blockIdx.y;
  const int b = bh >> 3, h = bh & 7;
  const int t = threadIdx.x;
  {
    int sl = t >> 2, dg = (t & 3) * 16;
    const bf16* src = qkv + (size_t)(b * Ss + bx * 64 + sl) * 1536 + 1024 + h * 64 + dg;
    *(bf16x8*)&tile[sl][dg]     = *(const bf16x8*)(src);
    *(bf16x8*)&tile[sl][dg + 8] = *(const bf16x8*)(src + 8);
  }
  __syncthreads();
  {
    int dl = t >> 2, sg = (t & 3) * 16;
    bf16* dst = vT + ((size_t)bh * 64 + dl) * Ss + bx * 64 + sg;
    alignas(16) bf16 tmp[16];
#pragma unroll
    for (int i = 0; i < 16; i++) tmp[i] = tile[sg + i][dl];
    *(bf16x8*)dst       = *(bf16x8*)tmp;
    *(bf16x8*)(dst + 8) = *(bf16x8*)(tmp + 8);
  }
}

// ---------------- MFMA flash attention ----------------
// qkv bf16 [NT,1536] (q pre-scaled by 1/sqrt(D) | k | v), vT bf16 [B*H,64,Ss].
// grid (32, B*H) = 512 blocks, 128 threads = 2 waves; wave owns 16 q-rows
// (QBLK=32/block). Work-descending: qt = 31 - bx. K-tiles of 64 keys.
// K/V fragments straight from global (L2-resident); only P goes via LDS.
__global__ __launch_bounds__(128) void attn_mfma(const bf16* __restrict__ qkv,
                                                 const bf16* __restrict__ vT,
                                                 bf16* __restrict__ o) {
  __shared__ alignas(16) bf16 P[2][16][72];
  const int t = threadIdx.x;
  const int w = t >> 6, lane = t & 63;
  const int hi = lane >> 4, lm = lane & 15;
  const int qt = 31 - (int)blockIdx.x;      // big blocks first
  const int bh = blockIdx.y;
  const int b = bh >> 3, h = bh & 7;
  const int hcol = h * 64;
  const size_t rb = (size_t)b * Ss * 1536;
  const int q0 = qt * 32 + w * 16;          // wave's first q row (within seq)

  // Q A-fragments (d = 0..31, 32..63), q already scaled
  bf16x8 qf[2];
  {
    const bf16* qp = qkv + rb + (size_t)(q0 + lm) * 1536 + hcol + hi * 8;
    qf[0] = *(const bf16x8*)qp;
    qf[1] = *(const bf16x8*)(qp + 32);
  }
  f32x4 Oacc[4];
#pragma unroll
  for (int i = 0; i < 4; i++) Oacc[i] = (f32x4){0.f, 0.f, 0.f, 0.f};
  float m[4] = {-INFINITY, -INFINITY, -INFINITY, -INFINITY};
  float l[4] = {0.f, 0.f, 0.f, 0.f};

  const int ct = qt >> 1;
  const bf16* kbase = qkv + rb + 512 + hcol;
  const bf16* vbase = vT + (size_t)bh * 64 * Ss;

  for (int c = 0; c <= ct; c++) {
    // ---- scores S[16q x 64k] via MFMA, K frags from global ----
    f32x4 S[4];
#pragma unroll
    for (int tt = 0; tt < 4; tt++) S[tt] = (f32x4){0.f, 0.f, 0.f, 0.f};
#pragma unroll
    for (int tt = 0; tt < 4; tt++) {
      const bf16* kp = kbase + (size_t)(c * 64 + tt * 16 + lm) * 1536 + hi * 8;
      bf16x8 k0 = *(const bf16x8*)kp;
      bf16x8 k1 = *(const bf16x8*)(kp + 32);
      S[tt] = __builtin_amdgcn_mfma_f32_16x16x32_bf16(qf[0], k0, S[tt], 0, 0, 0);
      S[tt] = __builtin_amdgcn_mfma_f32_16x16x32_bf16(qf[1], k1, S[tt], 0, 0, 0);
    }
    if (c == ct) {  // causal mask on the last tile
#pragma unroll
      for (int tt = 0; tt < 4; tt++) {
        int key = c * 64 + tt * 16 + lm;
#pragma unroll
        for (int r = 0; r < 4; r++) {
          if (key > q0 + hi * 4 + r) S[tt][r] = -INFINITY;
        }
      }
    }
    // ---- online softmax (row r lives in 16-lane group sharing `hi`) ----
    float mn[4], al[4];
#pragma unroll
    for (int r = 0; r < 4; r++) {
      float mx = fmaxf(fmaxf(S[0][r], S[1][r]), fmaxf(S[2][r], S[3][r]));
#pragma unroll
      for (int off = 1; off < 16; off <<= 1) mx = fmaxf(mx, __shfl_xor(mx, off, 64));
      mn[r] = fmaxf(m[r], mx);
      al[r] = __expf(m[r] - mn[r]);   // 0 on first tile
      m[r] = mn[r];
    }
    float p[4][4];
#pragma unroll
    for (int tt = 0; tt < 4; tt++)
#pragma unroll
      for (int r = 0; r < 4; r++) p[tt][r] = __expf(S[tt][r] - mn[r]);
#pragma unroll
    for (int r = 0; r < 4; r++) {
      float s = p[0][r] + p[1][r] + p[2][r] + p[3][r];
#pragma unroll
      for (int off = 1; off < 16; off <<= 1) s += __shfl_xor(s, off, 64);
      l[r] = l[r] * al[r] + s;
    }
#pragma unroll
    for (int i = 0; i < 4; i++) {
      Oacc[i][0] *= al[0]; Oacc[i][1] *= al[1];
      Oacc[i][2] *= al[2]; Oacc[i][3] *= al[3];
    }
    // ---- P (C-layout) -> LDS bf16 (wave-private; no block barrier needed) ----
#pragma unroll
    for (int tt = 0; tt < 4; tt++)
#pragma unroll
      for (int r = 0; r < 4; r++)
        P[w][hi * 4 + r][tt * 16 + lm] = __float2bfloat16(p[tt][r]);
    // ---- PV: A = P from LDS, B = V^T frags from global ----
#pragma unroll
    for (int e = 0; e < 2; e++) {
      bf16x8 pa = *(const bf16x8*)&P[w][lm][e * 32 + hi * 8];
#pragma unroll
      for (int tt = 0; tt < 4; tt++) {
        const bf16* vp = vbase + (size_t)(tt * 16 + lm) * Ss + c * 64 + e * 32 + hi * 8;
        bf16x8 vf = *(const bf16x8*)vp;
        Oacc[tt] = __builtin_amdgcn_mfma_f32_16x16x32_bf16(pa, vf, Oacc[tt], 0, 0, 0);
      }
    }
  }
  // ---- epilogue ----
  float inv[4] = {1.f / l[0], 1.f / l[1], 1.f / l[2], 1.f / l[3]};
  bf16* ob = o + (size_t)(b * Ss + q0) * Dd + hcol;
#pragma unroll
  for (int tt = 0; tt < 4; tt++)
#pragma unroll
    for (int r = 0; r < 4; r++)
      ob[(size_t)(hi * 4 + r) * Dd + tt * 16 + lm] = __float2bfloat16(Oacc[tt][r] * inv[r]);
}

// ---------------- loss ----------------
__global__ __launch_bounds__(256) void nll_kernel(const float* __restrict__ logits,
                                                  const int* __restrict__ idx,
                                                  const int* __restrict__ masks,
                                                  float* __restrict__ row_nll) {
  __shared__ float red[256];
  int row = blockIdx.x;
  int b = row >> 10, s = row & (Ss - 1);
  const float* lr = logits + (size_t)row * Vv;
  float mx = -INFINITY;
  for (int j = threadIdx.x; j < Vv; j += 256) mx = fmaxf(mx, lr[j]);
  red[threadIdx.x] = mx;
  __syncthreads();
  for (int st = 128; st > 0; st >>= 1) {
    if (threadIdx.x < st) red[threadIdx.x] = fmaxf(red[threadIdx.x], red[threadIdx.x + st]);
    __syncthreads();
  }
  mx = red[0];
  __syncthreads();
  float sum = 0.f;
  for (int j = threadIdx.x; j < Vv; j += 256) sum += __expf(lr[j] - mx);
  red[threadIdx.x] = sum;
  __syncthreads();
  for (int st = 128; st > 0; st >>= 1) {
    if (threadIdx.x < st) red[threadIdx.x] += red[threadIdx.x + st];
    __syncthreads();
  }
  if (threadIdx.x == 0) {
    int target = idx[b * (Ss + 1) + s + 1];
    float nll = logf(red[0]) + mx - lr[target];
    row_nll[row] = nll * (float)masks[row];
  }
}

__global__ __launch_bounds__(256) void loss_reduce_kernel(const float* __restrict__ row_nll,
                                                          float* __restrict__ out_loss) {
  __shared__ float red[256];
  float s = 0.f;
  for (int i = threadIdx.x; i < NT; i += 256) s += row_nll[i];
  red[threadIdx.x] = s;
  __syncthreads();
  for (int st = 128; st > 0; st >>= 1) {
    if (threadIdx.x < st) red[threadIdx.x] += red[threadIdx.x + st];
    __syncthreads();
  }
  if (threadIdx.x == 0) out_loss[0] = red[0] * (1.f / NT);
}

extern "C" void kernel_launch(void* const* d_in, const int* in_sizes, int n_in,
                              void* d_out, int out_size, void* d_ws, size_t ws_size,
                              hipStream_t stream) {
  const int*   idx   = (const int*)d_in[0];
  const int*   masks = (const int*)d_in[1];
  const float* tok   = (const float*)d_in[2];
  const float* pos   = (const float*)d_in[3];
  const float* Wq    = (const float*)d_in[4];
  const float* bq    = (const float*)d_in[5];
  const float* Wk    = (const float*)d_in[6];
  const float* bk    = (const float*)d_in[7];
  const float* Wv    = (const float*)d_in[8];
  const float* bv    = (const float*)d_in[9];
  const float* Wo    = (const float*)d_in[10];
  const float* bo    = (const float*)d_in[11];
  const float* ln1g  = (const float*)d_in[12];
  const float* ln1b  = (const float*)d_in[13];
  const float* W1    = (const float*)d_in[14];
  const float* b1    = (const float*)d_in[15];
  const float* W2    = (const float*)d_in[16];
  const float* b2    = (const float*)d_in[17];
  const float* ln2g  = (const float*)d_in[18];
  const float* ln2b  = (const float*)d_in[19];
  const float* lnfg  = (const float*)d_in[20];
  const float* lnfb  = (const float*)d_in[21];
  const float* headw = (const float*)d_in[22];

  float* out = (float*)d_out;

  // workspace layout
  char* p = (char*)d_ws;
  auto alloc = [&](size_t bytes) { char* r = p; p += (bytes + 255) & ~255ull; return r; };
  float* x     = (float*)alloc((size_t)NT * Dd * 4);
  bf16*  h     = (bf16*) alloc((size_t)NT * Dd * 2);
  bf16*  qkvb  = (bf16*) alloc((size_t)NT * 1536 * 2);
  bf16*  vT    = (bf16*) alloc((size_t)Bb * Hh * 64 * Ss * 2);
  bf16*  ob    = (bf16*) alloc((size_t)NT * Dd * 2);
  bf16*  mlp   = (bf16*) alloc((size_t)NT * Dff * 2);
  float* rnll  = (float*)alloc((size_t)NT * 4);
  bf16*  WqkvT = (bf16*) alloc((size_t)Ll * 1536 * 512 * 2);
  bf16*  WoT   = (bf16*) alloc((size_t)Ll * 512 * 512 * 2);
  bf16*  W1T   = (bf16*) alloc((size_t)Ll * 2048 * 512 * 2);
  bf16*  W2T   = (bf16*) alloc((size_t)Ll * 512 * 2048 * 2);
  bf16*  headT = (bf16*) alloc((size_t)Vpad * 512 * 2);
  float* bqkvc = (float*)alloc((size_t)Ll * 1536 * 4);

  const long DD = (long)Dd * Dd;
  // prep: weight transpose+convert (q-scale folded into Wq/bq)
  transpose_bf16<<<dim3(16, 16, Ll), 256, 0, stream>>>(Wq, WqkvT,               512, 512, 512,  DD, 1536L * 512, INV_SCALE);
  transpose_bf16<<<dim3(16, 16, Ll), 256, 0, stream>>>(Wk, WqkvT + 512 * 512,   512, 512, 512,  DD, 1536L * 512, 1.f);
  transpose_bf16<<<dim3(16, 16, Ll), 256, 0, stream>>>(Wv, WqkvT + 1024 * 512,  512, 512, 512,  DD, 1536L * 512, 1.f);
  transpose_bf16<<<dim3(16, 16, Ll), 256, 0, stream>>>(Wo, WoT,                 512, 512, 512,  DD, DD, 1.f);
  transpose_bf16<<<dim3(64, 16, Ll), 256, 0, stream>>>(W1, W1T,                 512, 2048, 2048, (long)512 * 2048, (long)2048 * 512, 1.f);
  transpose_bf16<<<dim3(16, 64, Ll), 256, 0, stream>>>(W2, W2T,                 2048, 512, 512, (long)2048 * 512, (long)512 * 2048, 1.f);
  transpose_bf16<<<dim3(Vpad / 32, 16, 1), 256, 0, stream>>>(headw, headT,      512, Vv, Vpad,  0, 0, 1.f);
  concat_bias<<<(Ll * 1536 + 255) / 256, 256, 0, stream>>>(bq, bk, bv, bqkvc);

  embed_kernel<<<(NT * Dd + 255) / 256, 256, 0, stream>>>(idx, masks, tok, pos, x);

  for (int l = 0; l < Ll; l++) {
    ln_kernel<<<NT / 4, 256, 0, stream>>>(x, ln1g + (size_t)l * Dd, ln1b + (size_t)l * Dd, h);
    mfma_gemm<<<dim3(12, 16), 256, 0, stream>>>(h, WqkvT + (size_t)l * 1536 * 512,
        bqkvc + (size_t)l * 1536, nullptr, nullptr, qkvb, NT, 1536, 512, 0);
    v_transpose<<<dim3(Ss / 64, Bb * Hh), 256, 0, stream>>>(qkvb, vT);
    attn_mfma<<<dim3(32, Bb * Hh), 128, 0, stream>>>(qkvb, vT, ob);
    mfma_gemm<<<dim3(4, 16), 256, 0, stream>>>(ob, WoT + (size_t)l * DD,
        bo + (size_t)l * Dd, x, x, nullptr, NT, 512, 512, 0);
    ln_kernel<<<NT / 4, 256, 0, stream>>>(x, ln2g + (size_t)l * Dd, ln2b + (size_t)l * Dd, h);
    mfma_gemm<<<dim3(16, 16), 256, 0, stream>>>(h, W1T + (size_t)l * Dff * Dd,
        b1 + (size_t)l * Dff, nullptr, nullptr, mlp, NT, 2048, 512, 1);
    mfma_gemm<<<dim3(4, 16), 256, 0, stream>>>(mlp, W2T + (size_t)l * Dff * Dd,
        b2 + (size_t)l * Dd, x, x, nullptr, NT, 512, 2048, 0);
  }

  ln_kernel<<<NT / 4, 256, 0, stream>>>(x, lnfg, lnfb, h);
  mfma_gemm<<<dim3(Vpad / 128, 16), 256, 0, stream>>>(h, headT, nullptr, nullptr,
      out, nullptr, NT, Vv, 512, 0);

  nll_kernel<<<NT, 256, 0, stream>>>(out, idx, masks, rnll);
  loss_reduce_kernel<<<1, 256, 0, stream>>>(rnll, out + (size_t)NT * Vv);
}

// Round 3
// 1822.748 us; speedup vs baseline: 1.8615x; 1.2262x over previous
//
#include <hip/hip_runtime.h>
#include <hip/hip_bf16.h>
#include <math.h>

constexpr int Vv   = 50257;
constexpr int Vpad = 50304;          // 393 * 128
constexpr int Dd   = 512;
constexpr int Hh   = 8;
constexpr int Ll   = 6;
constexpr int Ss   = 1024;
constexpr int Bb   = 2;
constexpr int NT   = Bb * Ss;        // 2048
constexpr int Dff  = 2048;
constexpr int PCH  = Vpad / 64;      // 786 softmax partial chunks per row
constexpr float INV_SCALE = 0.04419417382415922f; // 1/sqrt(512)

typedef __hip_bfloat16 bf16;
typedef __attribute__((ext_vector_type(8))) short bf16x8;
typedef __attribute__((ext_vector_type(4))) float f32x4;

__device__ inline float wave_sum(float x) {
#pragma unroll
  for (int off = 32; off > 0; off >>= 1) x += __shfl_xor(x, off, 64);
  return x;
}

// async global->LDS, 16B per lane, dst = wave-uniform base + lane*16
__device__ inline void gl_lds16(const bf16* g, bf16* l) {
  __builtin_amdgcn_global_load_lds((__attribute__((address_space(1))) void*)g,
                                   (__attribute__((address_space(3))) void*)l,
                                   16, 0, 0);
}

// ---------------- prep: transpose fp32 [K,N] -> bf16 [Npad,K] (times scale) ----
__global__ __launch_bounds__(256) void transpose_bf16(
    const float* __restrict__ src, bf16* __restrict__ dst,
    int K, int N, int Npad, long srcStride, long dstStride, float scale) {
  __shared__ float tile[32][33];
  const float* s = src + (size_t)blockIdx.z * srcStride;
  bf16* d = dst + (size_t)blockIdx.z * dstStride;
  int n0 = blockIdx.x * 32, k0 = blockIdx.y * 32;
  int tr = threadIdx.x >> 5, tc = threadIdx.x & 31;
#pragma unroll
  for (int i = 0; i < 4; i++) {
    int k = k0 + tr + i * 8, n = n0 + tc;
    tile[tr + i * 8][tc] = (k < K && n < N) ? s[(size_t)k * N + n] * scale : 0.f;
  }
  __syncthreads();
#pragma unroll
  for (int i = 0; i < 4; i++) {
    int n = n0 + tr + i * 8, k = k0 + tc;
    if (n < Npad && k < K) d[(size_t)n * K + k] = __float2bfloat16(tile[tc][tr + i * 8]);
  }
}

__global__ void concat_bias(const float* __restrict__ bq, const float* __restrict__ bk,
                            const float* __restrict__ bv, float* __restrict__ dst) {
  int i = blockIdx.x * 256 + threadIdx.x;
  if (i >= Ll * 1536) return;
  int l = i / 1536, j = i - l * 1536;
  float v = (j < 512) ? bq[l * 512 + j] * INV_SCALE
          : (j < 1024) ? bk[l * 512 + j - 512]
                       : bv[l * 512 + j - 1024];
  dst[i] = v;
}

// ---------------- embed ----------------
__global__ void embed_kernel(const int* __restrict__ idx, const int* __restrict__ masks,
                             const float* __restrict__ tok, const float* __restrict__ pos,
                             float* __restrict__ x) {
  int i = blockIdx.x * blockDim.x + threadIdx.x;
  if (i >= NT * Dd) return;
  int d = i & (Dd - 1);
  int row = i >> 9;
  int s = row & (Ss - 1);
  int b = row >> 10;
  int t = idx[b * (Ss + 1) + s];
  float m = (float)masks[row];
  x[i] = (tok[(size_t)t * Dd + d] + pos[s * Dd + d]) * m;
}

// ---------------- LayerNorm: fp32 in, bf16 out; 4 rows/block ----------------
__global__ __launch_bounds__(256) void ln_kernel(const float* __restrict__ x,
                                                 const float* __restrict__ g,
                                                 const float* __restrict__ b,
                                                 bf16* __restrict__ out) {
  int row = blockIdx.x * 4 + (threadIdx.x >> 6);
  int lane = threadIdx.x & 63;
  const float* xr = x + (size_t)row * Dd;
  float vals[8];
  float s = 0.f;
#pragma unroll
  for (int i = 0; i < 8; i++) { vals[i] = xr[lane + i * 64]; s += vals[i]; }
  s = wave_sum(s);
  float mean = s * (1.f / Dd);
  float vs = 0.f;
#pragma unroll
  for (int i = 0; i < 8; i++) { float dd = vals[i] - mean; vs += dd * dd; }
  vs = wave_sum(vs);
  float rstd = rsqrtf(vs * (1.f / Dd) + 1e-5f);
  bf16* orow = out + (size_t)row * Dd;
#pragma unroll
  for (int i = 0; i < 8; i++) {
    int d = lane + i * 64;
    orow[d] = __float2bfloat16((vals[i] - mean) * rstd * g[d] + b[d]);
  }
}

// ---------------- MFMA GEMM (m97 structure), M fixed = 2048 ----------------
// 1D grid, XCD-bijective swizzle, M-block fastest (blocks sharing a B-tile
// land on the same XCD for L2 reuse). Optional epilogues:
//   Catomic: split-K atomicAdd into fp32 buffer (resid already in place)
//   vTout:   scatter-write transposed V copy (QKV gemm, cols >= 1024)
//   partials:per-row softmax partials (max, sumexp) over 64-col wave slices
__global__ __launch_bounds__(256) void mfma_gemm(
    const bf16* __restrict__ A, const bf16* __restrict__ Bt,
    const float* __restrict__ bias, const float* __restrict__ resid,
    float* __restrict__ Cf, bf16* __restrict__ Cb,
    bf16* __restrict__ vTout, float* __restrict__ partials,
    float* __restrict__ Catomic,
    int N, int K, int act, int klen) {
  __shared__ bf16 As[128 * 32];
  __shared__ bf16 Bs[128 * 32];
  const int t = threadIdx.x;
  const int w = t >> 6, lane = t & 63;
  // XCD swizzle (gridDim.x divisible by 8), then m-block fastest (16 blocks)
  const int q8 = gridDim.x >> 3;
  const int lin = blockIdx.x;
  const int swz = (lin & 7) * q8 + (lin >> 3);
  const int m0 = (swz & 15) << 7;
  const int n0 = (swz >> 4) << 7;
  const int rr = lane >> 2;            // 0..15 rows per load inst
  const int cc = (lane & 3) * 8;       // elem col within BK
  const bf16* ap0 = A  + (size_t)(m0 + w * 32 + rr) * K + cc;
  const bf16* ap1 = ap0 + (size_t)16 * K;
  const bf16* bp0 = Bt + (size_t)(n0 + w * 32 + rr) * K + cc;
  const bf16* bp1 = bp0 + (size_t)16 * K;
  bf16* as0 = As + w * 32 * 32;
  bf16* as1 = as0 + 16 * 32;
  bf16* bs0 = Bs + w * 32 * 32;
  bf16* bs1 = bs0 + 16 * 32;
  const int wr = (w >> 1) * 64, wc = (w & 1) * 64;
  const int lm = lane & 15, lk = (lane >> 4) * 8;
  f32x4 acc[4][4];
#pragma unroll
  for (int i = 0; i < 4; i++)
#pragma unroll
    for (int j = 0; j < 4; j++) acc[i][j] = (f32x4){0.f, 0.f, 0.f, 0.f};

  const int kbeg = blockIdx.z * klen;
  const int kend = kbeg + klen;
  for (int k0 = kbeg; k0 < kend; k0 += 32) {
    __syncthreads();
    gl_lds16(ap0 + k0, as0);
    gl_lds16(ap1 + k0, as1);
    gl_lds16(bp0 + k0, bs0);
    gl_lds16(bp1 + k0, bs1);
    __syncthreads();
    bf16x8 af[4], bg[4];
#pragma unroll
    for (int i = 0; i < 4; i++)
      af[i] = *(const bf16x8*)(As + (wr + i * 16 + lm) * 32 + lk);
#pragma unroll
    for (int j = 0; j < 4; j++)
      bg[j] = *(const bf16x8*)(Bs + (wc + j * 16 + lm) * 32 + lk);
#pragma unroll
    for (int i = 0; i < 4; i++)
#pragma unroll
      for (int j = 0; j < 4; j++)
        acc[i][j] = __builtin_amdgcn_mfma_f32_16x16x32_bf16(af[i], bg[j], acc[i][j], 0, 0, 0);
  }

  const int r4 = (lane >> 4) * 4;
  if (Catomic) {  // split-K accumulate; bias added by z==0 slice only
    const float bs = (blockIdx.z == 0) ? 1.f : 0.f;
#pragma unroll
    for (int i = 0; i < 4; i++)
#pragma unroll
      for (int j = 0; j < 4; j++) {
        int col = n0 + wc + j * 16 + lm;
        float bi = bias[col] * bs;
#pragma unroll
        for (int r = 0; r < 4; r++) {
          int row = m0 + wr + i * 16 + r4 + r;
          atomicAdd(&Catomic[(size_t)row * N + col], acc[i][j][r] + bi);
        }
      }
    return;
  }
#pragma unroll
  for (int i = 0; i < 4; i++) {
#pragma unroll
    for (int j = 0; j < 4; j++) {
      int col = n0 + wc + j * 16 + lm;
      if (col >= N) continue;
      float bi = bias ? bias[col] : 0.f;
#pragma unroll
      for (int r = 0; r < 4; r++) {
        int row = m0 + wr + i * 16 + r4 + r;
        float v = acc[i][j][r] + bi;
        if (act) v = 0.5f * v * (1.f + erff(v * 0.70710678118654752f));
        if (resid) v += resid[(size_t)row * N + col];
        if (Cf) Cf[(size_t)row * N + col] = v;
        else    Cb[(size_t)row * N + col] = __float2bfloat16(v);
        if (vTout && col >= 1024) {  // V region: also write transposed copy
          int dcol = col - 1024;
          int b = row >> 10;
          vTout[((size_t)((b << 3) + (dcol >> 6)) * 64 + (dcol & 63)) * Ss + (row & (Ss - 1))]
              = __float2bfloat16(v);
        }
      }
    }
  }
  if (partials) {  // per-row softmax partials over this wave's 64 cols
#pragma unroll
    for (int i = 0; i < 4; i++) {
#pragma unroll
      for (int r = 0; r < 4; r++) {
        float mx = -INFINITY;
#pragma unroll
        for (int j = 0; j < 4; j++) {
          int col = n0 + wc + j * 16 + lm;
          if (col < N) mx = fmaxf(mx, acc[i][j][r]);
        }
#pragma unroll
        for (int off = 1; off < 16; off <<= 1) mx = fmaxf(mx, __shfl_xor(mx, off, 64));
        float se = 0.f;
#pragma unroll
        for (int j = 0; j < 4; j++) {
          int col = n0 + wc + j * 16 + lm;
          if (col < N) se += __expf(acc[i][j][r] - mx);
        }
#pragma unroll
        for (int off = 1; off < 16; off <<= 1) se += __shfl_xor(se, off, 64);
        if (lm == 0) {
          int row = m0 + wr + i * 16 + r4 + r;
          int chunk = (n0 + wc) >> 6;
          ((float2*)partials)[(size_t)row * PCH + chunk] = make_float2(mx, se);
        }
      }
    }
  }
}

// ---------------- MFMA flash attention ----------------
// qkv bf16 [NT,1536] (q pre-scaled | k | v), vT bf16 [B*H,64,Ss].
// grid (B*H, 32) = 512 blocks, 128 threads = 2 waves; wave owns 16 q-rows.
// Work-descending: qt = 31 - blockIdx.y (y=0 dispatched first).
__global__ __launch_bounds__(128) void attn_mfma(const bf16* __restrict__ qkv,
                                                 const bf16* __restrict__ vT,
                                                 bf16* __restrict__ o) {
  __shared__ alignas(16) bf16 P[2][16][72];
  const int t = threadIdx.x;
  const int w = t >> 6, lane = t & 63;
  const int hi = lane >> 4, lm = lane & 15;
  const int qt = 31 - (int)blockIdx.y;      // big blocks first
  const int bh = blockIdx.x;
  const int b = bh >> 3, h = bh & 7;
  const int hcol = h * 64;
  const size_t rb = (size_t)b * Ss * 1536;
  const int q0 = qt * 32 + w * 16;          // wave's first q row (within seq)

  bf16x8 qf[2];
  {
    const bf16* qp = qkv + rb + (size_t)(q0 + lm) * 1536 + hcol + hi * 8;
    qf[0] = *(const bf16x8*)qp;
    qf[1] = *(const bf16x8*)(qp + 32);
  }
  f32x4 Oacc[4];
#pragma unroll
  for (int i = 0; i < 4; i++) Oacc[i] = (f32x4){0.f, 0.f, 0.f, 0.f};
  float m[4] = {-INFINITY, -INFINITY, -INFINITY, -INFINITY};
  float l[4] = {0.f, 0.f, 0.f, 0.f};

  const int ct = qt >> 1;
  const bf16* kbase = qkv + rb + 512 + hcol;
  const bf16* vbase = vT + (size_t)bh * 64 * Ss;

  for (int c = 0; c <= ct; c++) {
    f32x4 S[4];
#pragma unroll
    for (int tt = 0; tt < 4; tt++) S[tt] = (f32x4){0.f, 0.f, 0.f, 0.f};
#pragma unroll
    for (int tt = 0; tt < 4; tt++) {
      const bf16* kp = kbase + (size_t)(c * 64 + tt * 16 + lm) * 1536 + hi * 8;
      bf16x8 k0 = *(const bf16x8*)kp;
      bf16x8 k1 = *(const bf16x8*)(kp + 32);
      S[tt] = __builtin_amdgcn_mfma_f32_16x16x32_bf16(qf[0], k0, S[tt], 0, 0, 0);
      S[tt] = __builtin_amdgcn_mfma_f32_16x16x32_bf16(qf[1], k1, S[tt], 0, 0, 0);
    }
    if (c == ct) {  // causal mask on the last tile
#pragma unroll
      for (int tt = 0; tt < 4; tt++) {
        int key = c * 64 + tt * 16 + lm;
#pragma unroll
        for (int r = 0; r < 4; r++) {
          if (key > q0 + hi * 4 + r) S[tt][r] = -INFINITY;
        }
      }
    }
    float mn[4], al[4];
#pragma unroll
    for (int r = 0; r < 4; r++) {
      float mx = fmaxf(fmaxf(S[0][r], S[1][r]), fmaxf(S[2][r], S[3][r]));
#pragma unroll
      for (int off = 1; off < 16; off <<= 1) mx = fmaxf(mx, __shfl_xor(mx, off, 64));
      mn[r] = fmaxf(m[r], mx);
      al[r] = __expf(m[r] - mn[r]);   // 0 on first tile
      m[r] = mn[r];
    }
    float p[4][4];
#pragma unroll
    for (int tt = 0; tt < 4; tt++)
#pragma unroll
      for (int r = 0; r < 4; r++) p[tt][r] = __expf(S[tt][r] - mn[r]);
#pragma unroll
    for (int r = 0; r < 4; r++) {
      float s = p[0][r] + p[1][r] + p[2][r] + p[3][r];
#pragma unroll
      for (int off = 1; off < 16; off <<= 1) s += __shfl_xor(s, off, 64);
      l[r] = l[r] * al[r] + s;
    }
#pragma unroll
    for (int i = 0; i < 4; i++) {
      Oacc[i][0] *= al[0]; Oacc[i][1] *= al[1];
      Oacc[i][2] *= al[2]; Oacc[i][3] *= al[3];
    }
#pragma unroll
    for (int tt = 0; tt < 4; tt++)
#pragma unroll
      for (int r = 0; r < 4; r++)
        P[w][hi * 4 + r][tt * 16 + lm] = __float2bfloat16(p[tt][r]);
#pragma unroll
    for (int e = 0; e < 2; e++) {
      bf16x8 pa = *(const bf16x8*)&P[w][lm][e * 32 + hi * 8];
#pragma unroll
      for (int tt = 0; tt < 4; tt++) {
        const bf16* vp = vbase + (size_t)(tt * 16 + lm) * Ss + c * 64 + e * 32 + hi * 8;
        bf16x8 vf = *(const bf16x8*)vp;
        Oacc[tt] = __builtin_amdgcn_mfma_f32_16x16x32_bf16(pa, vf, Oacc[tt], 0, 0, 0);
      }
    }
  }
  float inv[4] = {1.f / l[0], 1.f / l[1], 1.f / l[2], 1.f / l[3]};
  bf16* ob = o + (size_t)(b * Ss + q0) * Dd + hcol;
#pragma unroll
  for (int tt = 0; tt < 4; tt++)
#pragma unroll
    for (int r = 0; r < 4; r++)
      ob[(size_t)(hi * 4 + r) * Dd + tt * 16 + lm] = __float2bfloat16(Oacc[tt][r] * inv[r]);
}

// ---------------- loss: combine per-chunk softmax partials ----------------
__global__ __launch_bounds__(256) void nll_reduce(const float2* __restrict__ partials,
                                                  const float* __restrict__ logits,
                                                  const int* __restrict__ idx,
                                                  const int* __restrict__ masks,
                                                  float* __restrict__ row_nll) {
  __shared__ float sm[256], ss[256];
  const int row = blockIdx.x;
  const float2* pr = partials + (size_t)row * PCH;
  float m = -INFINITY, s = 0.f;
  for (int j = threadIdx.x; j < PCH; j += 256) {
    float2 p = pr[j];
    float mn = fmaxf(m, p.x);
    s = s * __expf(m - mn) + p.y * __expf(p.x - mn);
    m = mn;
  }
  sm[threadIdx.x] = m; ss[threadIdx.x] = s;
  __syncthreads();
  for (int st = 128; st > 0; st >>= 1) {
    if (threadIdx.x < st) {
      float m2 = sm[threadIdx.x + st], s2 = ss[threadIdx.x + st];
      float mn = fmaxf(sm[threadIdx.x], m2);
      ss[threadIdx.x] = ss[threadIdx.x] * __expf(sm[threadIdx.x] - mn) + s2 * __expf(m2 - mn);
      sm[threadIdx.x] = mn;
    }
    __syncthreads();
  }
  if (threadIdx.x == 0) {
    int b = row >> 10, sq = row & (Ss - 1);
    int target = idx[b * (Ss + 1) + sq + 1];
    float tv = logits[(size_t)row * Vv + target];
    row_nll[row] = (logf(ss[0]) + sm[0] - tv) * (float)masks[row];
  }
}

__global__ __launch_bounds__(256) void loss_reduce_kernel(const float* __restrict__ row_nll,
                                                          float* __restrict__ out_loss) {
  __shared__ float red[256];
  float s = 0.f;
  for (int i = threadIdx.x; i < NT; i += 256) s += row_nll[i];
  red[threadIdx.x] = s;
  __syncthreads();
  for (int st = 128; st > 0; st >>= 1) {
    if (threadIdx.x < st) red[threadIdx.x] += red[threadIdx.x + st];
    __syncthreads();
  }
  if (threadIdx.x == 0) out_loss[0] = red[0] * (1.f / NT);
}

extern "C" void kernel_launch(void* const* d_in, const int* in_sizes, int n_in,
                              void* d_out, int out_size, void* d_ws, size_t ws_size,
                              hipStream_t stream) {
  const int*   idx   = (const int*)d_in[0];
  const int*   masks = (const int*)d_in[1];
  const float* tok   = (const float*)d_in[2];
  const float* pos   = (const float*)d_in[3];
  const float* Wq    = (const float*)d_in[4];
  const float* bq    = (const float*)d_in[5];
  const float* Wk    = (const float*)d_in[6];
  const float* bk    = (const float*)d_in[7];
  const float* Wv    = (const float*)d_in[8];
  const float* bv    = (const float*)d_in[9];
  const float* Wo    = (const float*)d_in[10];
  const float* bo    = (const float*)d_in[11];
  const float* ln1g  = (const float*)d_in[12];
  const float* ln1b  = (const float*)d_in[13];
  const float* W1    = (const float*)d_in[14];
  const float* b1    = (const float*)d_in[15];
  const float* W2    = (const float*)d_in[16];
  const float* b2    = (const float*)d_in[17];
  const float* ln2g  = (const float*)d_in[18];
  const float* ln2b  = (const float*)d_in[19];
  const float* lnfg  = (const float*)d_in[20];
  const float* lnfb  = (const float*)d_in[21];
  const float* headw = (const float*)d_in[22];

  float* out = (float*)d_out;

  // workspace layout (~109 MB; parts ALIASES dead activation buffers)
  char* p = (char*)d_ws;
  auto alloc = [&](size_t bytes) { char* r = p; p += (bytes + 255) & ~255ull; return r; };
  float* x     = (float*)alloc((size_t)NT * Dd * 4);
  bf16*  h     = (bf16*) alloc((size_t)NT * Dd * 2);
  bf16*  qkvb  = (bf16*) alloc((size_t)NT * 1536 * 2);
  bf16*  vT    = (bf16*) alloc((size_t)Bb * Hh * 64 * Ss * 2);
  bf16*  ob    = (bf16*) alloc((size_t)NT * Dd * 2);
  bf16*  mlp   = (bf16*) alloc((size_t)NT * Dff * 2);
  float* rnll  = (float*)alloc((size_t)NT * 4);
  bf16*  WqkvT = (bf16*) alloc((size_t)Ll * 1536 * 512 * 2);
  bf16*  WoT   = (bf16*) alloc((size_t)Ll * 512 * 512 * 2);
  bf16*  W1T   = (bf16*) alloc((size_t)Ll * 2048 * 512 * 2);
  bf16*  W2T   = (bf16*) alloc((size_t)Ll * 512 * 2048 * 2);
  bf16*  headT = (bf16*) alloc((size_t)Vpad * 512 * 2);
  float* bqkvc = (float*)alloc((size_t)Ll * 1536 * 4);
  // parts (NT*PCH*8 = 12.9 MB) reuses qkvb..mlp (18 MB, dead at head-gemm time)
  float* parts = (float*)qkvb;

  const long DD = (long)Dd * Dd;
  transpose_bf16<<<dim3(16, 16, Ll), 256, 0, stream>>>(Wq, WqkvT,               512, 512, 512,  DD, 1536L * 512, INV_SCALE);
  transpose_bf16<<<dim3(16, 16, Ll), 256, 0, stream>>>(Wk, WqkvT + 512 * 512,   512, 512, 512,  DD, 1536L * 512, 1.f);
  transpose_bf16<<<dim3(16, 16, Ll), 256, 0, stream>>>(Wv, WqkvT + 1024 * 512,  512, 512, 512,  DD, 1536L * 512, 1.f);
  transpose_bf16<<<dim3(16, 16, Ll), 256, 0, stream>>>(Wo, WoT,                 512, 512, 512,  DD, DD, 1.f);
  transpose_bf16<<<dim3(64, 16, Ll), 256, 0, stream>>>(W1, W1T,                 512, 2048, 2048, (long)512 * 2048, (long)2048 * 512, 1.f);
  transpose_bf16<<<dim3(16, 64, Ll), 256, 0, stream>>>(W2, W2T,                 2048, 512, 512, (long)2048 * 512, (long)512 * 2048, 1.f);
  transpose_bf16<<<dim3(Vpad / 32, 16, 1), 256, 0, stream>>>(headw, headT,      512, Vv, Vpad,  0, 0, 1.f);
  concat_bias<<<(Ll * 1536 + 255) / 256, 256, 0, stream>>>(bq, bk, bv, bqkvc);

  embed_kernel<<<(NT * Dd + 255) / 256, 256, 0, stream>>>(idx, masks, tok, pos, x);

  for (int l = 0; l < Ll; l++) {
    ln_kernel<<<NT / 4, 256, 0, stream>>>(x, ln1g + (size_t)l * Dd, ln1b + (size_t)l * Dd, h);
    // QKV gemm; also scatter-writes V^T
    mfma_gemm<<<dim3(192, 1, 1), 256, 0, stream>>>(h, WqkvT + (size_t)l * 1536 * 512,
        bqkvc + (size_t)l * 1536, nullptr, nullptr, qkvb, vT, nullptr, nullptr,
        1536, 512, 0, 512);
    attn_mfma<<<dim3(Bb * Hh, 32), 128, 0, stream>>>(qkvb, vT, ob);
    // Wo: split-K=2, atomic accumulate into x (residual already in x)
    mfma_gemm<<<dim3(64, 1, 2), 256, 0, stream>>>(ob, WoT + (size_t)l * DD,
        bo + (size_t)l * Dd, nullptr, nullptr, nullptr, nullptr, nullptr, x,
        512, 512, 0, 256);
    ln_kernel<<<NT / 4, 256, 0, stream>>>(x, ln2g + (size_t)l * Dd, ln2b + (size_t)l * Dd, h);
    mfma_gemm<<<dim3(256, 1, 1), 256, 0, stream>>>(h, W1T + (size_t)l * Dff * Dd,
        b1 + (size_t)l * Dff, nullptr, nullptr, mlp, nullptr, nullptr, nullptr,
        2048, 512, 1, 512);
    // W2: split-K=4, atomic accumulate into x
    mfma_gemm<<<dim3(64, 1, 4), 256, 0, stream>>>(mlp, W2T + (size_t)l * Dff * Dd,
        b2 + (size_t)l * Dd, nullptr, nullptr, nullptr, nullptr, nullptr, x,
        512, 2048, 0, 512);
  }

  ln_kernel<<<NT / 4, 256, 0, stream>>>(x, lnfg, lnfb, h);
  // head gemm writes logits + softmax partials (no logits re-read)
  mfma_gemm<<<dim3(Vpad / 128 * 16, 1, 1), 256, 0, stream>>>(h, headT, nullptr, nullptr,
      out, nullptr, nullptr, parts, nullptr, Vv, 512, 0, 512);

  nll_reduce<<<NT, 256, 0, stream>>>((const float2*)parts, out, idx, masks, rnll);
  loss_reduce_kernel<<<1, 256, 0, stream>>>(rnll, out + (size_t)NT * Vv);
}